// Round 4
// baseline (849.551 us; speedup 1.0000x reference)
//
#include <hip/hip_runtime.h>

// Problem constants: B=8, N=2048, C=768, H=12, D=64
#define SEQ   2048
#define NH    12
#define HD    64
#define CDIM  768

typedef _Float16 half8  __attribute__((ext_vector_type(8)));
typedef _Float16 half4v __attribute__((ext_vector_type(4)));
typedef float    f32x4  __attribute__((ext_vector_type(4)));

// 0.125 * log2(e): QK^T scores come out in log2 units -> softmax via exp2 (no mul)
#define QSCALE 0.18033688011112042f

__device__ __forceinline__ void load_lds16(const _Float16* g, _Float16* l) {
  __builtin_amdgcn_global_load_lds(
      (const __attribute__((address_space(1))) void*)g,
      (__attribute__((address_space(3))) void*)l, 16, 0, 0);
}

// ---------------- fp32 -> fp16 convert ----------------
__global__ void cvt_f32_f16(const float* __restrict__ in, _Float16* __restrict__ out, int n) {
  int i = (blockIdx.x * 256 + threadIdx.x) * 4;
  if (i >= n) return;
  float4 v = *(const float4*)(in + i);
  half4v o;
  o.x = (_Float16)v.x; o.y = (_Float16)v.y; o.z = (_Float16)v.z; o.w = (_Float16)v.w;
  *(half4v*)(out + i) = o;
}

// ---------------- GEMM: C[r][f] = sum_k A[r][k] * W[f][k] ----------------
// MODE 0: QKV projection epilogue -> scatter q (scaled by 0.125*log2e), k to
//         [B,H,N,D], v to [B,H,D,N].  MODE 1: fp32 out[r][f] + bias[f].
template <int MODE, int GX>
__global__ __launch_bounds__(256, 2) void gemm_f16(
    const _Float16* __restrict__ A, const _Float16* __restrict__ W,
    _Float16* __restrict__ qo, _Float16* __restrict__ ko, _Float16* __restrict__ vo,
    float* __restrict__ out, const float* __restrict__ bias) {
  __shared__ __align__(16) _Float16 As[128 * 64];
  __shared__ __align__(16) _Float16 Bs[128 * 64];

  const int tid  = threadIdx.x;
  const int wave = tid >> 6;
  const int lane = tid & 63;
  const int wm = wave >> 1, wn = wave & 1;
  const int l15 = lane & 15, lg = lane >> 4;

  // XCD-chunked swizzle (nwg % 8 == 0 for both launches)
  const int nwg = GX * gridDim.y;
  int id = blockIdx.y * GX + blockIdx.x;
  id = (id & 7) * (nwg >> 3) + (id >> 3);
  const int rowBase = (id / GX) * 128;
  const int colBase = (id % GX) * 128;

  const f32x4 fzero = {0.f, 0.f, 0.f, 0.f};
  f32x4 acc[4][4];
#pragma unroll
  for (int m = 0; m < 4; ++m)
#pragma unroll
    for (int n = 0; n < 4; ++n) acc[m][n] = fzero;

  for (int kt = 0; kt < CDIM; kt += 64) {
    __syncthreads();
#pragma unroll
    for (int p = 0; p < 4; ++p) {
      int c = tid + p * 256;
      int r = c >> 3, cb = (c & 7) * 8;  // 8 chunks of 16B per 64-elem row
      load_lds16(A + (size_t)(rowBase + r) * CDIM + kt + cb, As + c * 8);
      load_lds16(W + (size_t)(colBase + r) * CDIM + kt + cb, Bs + c * 8);
    }
    __syncthreads();
#pragma unroll
    for (int ks = 0; ks < 2; ++ks) {
      half8 af[4], bf[4];
#pragma unroll
      for (int m = 0; m < 4; ++m)
        af[m] = *(const half8*)(As + (wm * 64 + m * 16 + l15) * 64 + ks * 32 + lg * 8);
#pragma unroll
      for (int n = 0; n < 4; ++n)
        bf[n] = *(const half8*)(Bs + (wn * 64 + n * 16 + l15) * 64 + ks * 32 + lg * 8);
#pragma unroll
      for (int m = 0; m < 4; ++m)
#pragma unroll
        for (int n = 0; n < 4; ++n)
          acc[m][n] = __builtin_amdgcn_mfma_f32_16x16x32_f16(af[m], bf[n], acc[m][n], 0, 0, 0);
    }
  }

  // Epilogue. C/D frag: col = lane&15, row = (lane>>4)*4 + g
  if constexpr (MODE == 0) {
#pragma unroll
    for (int m = 0; m < 4; ++m) {
#pragma unroll
      for (int n = 0; n < 4; ++n) {
        int f = colBase + wn * 64 + n * 16 + l15;      // 0..2303
        int which = f / CDIM;
        int fr = f - which * CDIM;
        int h = fr >> 6, d = fr & 63;
#pragma unroll
        for (int g = 0; g < 4; ++g) {
          int r = rowBase + wm * 64 + m * 16 + lg * 4 + g;  // 0..16383
          int b = r >> 11, nn = r & 2047;
          float v = acc[m][n][g];
          size_t bh = (size_t)(b * NH + h);
          if (which == 0)      qo[(bh * SEQ + nn) * HD + d] = (_Float16)(v * QSCALE);
          else if (which == 1) ko[(bh * SEQ + nn) * HD + d] = (_Float16)v;
          else                 vo[(bh * HD + d) * SEQ + nn] = (_Float16)v;
        }
      }
    }
  } else {
#pragma unroll
    for (int m = 0; m < 4; ++m) {
#pragma unroll
      for (int n = 0; n < 4; ++n) {
        int f = colBase + wn * 64 + n * 16 + l15;
        float bv = bias[f];
#pragma unroll
        for (int g = 0; g < 4; ++g) {
          int r = rowBase + wm * 64 + m * 16 + lg * 4 + g;
          out[(size_t)r * CDIM + f] = acc[m][n][g] + bv;
        }
      }
    }
  }
}

// ---------------- Flash attention ----------------
// grid = 768 blocks (3/CU exactly), block = 512 (8 waves). Block owns 256
// q-rows; wave owns 32 (2 subtiles of 16); lane owns 2 queries (q = l15).
// S^T = mfma16x16x32(K,Q): lane holds S[key=ct*16+lg*4+g][q=l15] == the B-frag
// of mfma_f32_16x16x16f16, so P feeds PV straight from registers.
// PV: O^T = mfma16x16x16(V,P), A-frag = b64 from Vs with FULL 4-bit slot
// swizzle (slot = granule ^ (d&15)) -> 16 distinct bank-pairs per quarter-wave
// (conflict-free; the &14 DMA-compatible mask was a measured 2-way conflict).
// K staged by global_load_lds (pre-swizzled source); V register-staged so the
// odd-mask swizzle is possible. One barrier per tile, double-buffered.
// Softmax: defer-max keeps mo uniform -> common path has ZERO cross-lane ops;
// ls kept as per-lane partial, reduced once in the epilogue.
__global__ __launch_bounds__(512, 6) void attn_f16(
    const _Float16* __restrict__ qb, const _Float16* __restrict__ kb,
    const _Float16* __restrict__ vt, _Float16* __restrict__ ob) {
  __shared__ __align__(16) _Float16 Ks[2][64 * 64];
  __shared__ __align__(16) _Float16 Vs[2][64 * 64];

  const int tid  = threadIdx.x;
  const int wave = tid >> 6;
  const int lane = tid & 63;
  const int l15 = lane & 15, lg = lane >> 4;

  // XCD-chunked mapping: xcd = i&7 owns 12 heads x all 8 q-tiles -> K/V of a
  // head stays in one XCD's L2 (blocks of one head stream tiles in lockstep).
  const int i = blockIdx.y * gridDim.x + blockIdx.x;  // 0..767
  const int w = i >> 3;                               // 0..95
  const int bh = (i & 7) * NH + (w % NH);
  const int qt = w / NH;                              // 0..7

  const _Float16* qp = qb + (size_t)bh * SEQ * HD;
  const _Float16* kp = kb + (size_t)bh * SEQ * HD;
  const _Float16* vp = vt + (size_t)bh * SEQ * HD;  // Vt: [64 d][2048 keys]

  // Q fragments (pre-scaled): B-frag n = l15 = q, k = lg*8+j
  half8 qf[2][2];
#pragma unroll
  for (int qb2 = 0; qb2 < 2; ++qb2) {
    int qrow = qt * 256 + wave * 32 + qb2 * 16 + l15;
    qf[qb2][0] = *(const half8*)(qp + (size_t)qrow * HD + lg * 8);
    qf[qb2][1] = *(const half8*)(qp + (size_t)qrow * HD + 32 + lg * 8);
  }

  const f32x4 fzero = {0.f, 0.f, 0.f, 0.f};
  f32x4 o[2][4];
#pragma unroll
  for (int qb2 = 0; qb2 < 2; ++qb2)
#pragma unroll
    for (int dt = 0; dt < 4; ++dt) o[qb2][dt] = fzero;
  float mo[2] = {-3.0e38f, -3.0e38f}, ls[2] = {0.f, 0.f};

  // staging indices (tid 0..511 covers the full 64x64 tile once)
  const int sr = tid >> 3;            // row (K key-row / V d-row), 0..63
  const int sa = tid & 7;             // 16B chunk index, 0..7
  uint4 vreg;

  auto kv_issue = [&](int dstBuf, int kt) {
    // K: DMA, pre-swizzled source (dest linear = tid*16B)
    int x = sa * 16;
    const _Float16* kg = kp + (size_t)(kt * 64 + sr) * HD + ((x ^ ((sr & 7) << 4)) >> 1);
    load_lds16(kg, &Ks[dstBuf][0] + (size_t)tid * 8);
    // V: register load (16B = granules 2a, 2a+1 of row sr)
    vreg = *(const uint4*)(vp + (size_t)sr * SEQ + kt * 64 + sa * 8);
  };
  auto v_commit = [&](int dstBuf) {
    char* base = (char*)&Vs[dstBuf][0] + sr * 128;
    *(uint2*)(base + (((2 * sa)     ^ (sr & 15)) * 8)) = make_uint2(vreg.x, vreg.y);
    *(uint2*)(base + (((2 * sa + 1) ^ (sr & 15)) * 8)) = make_uint2(vreg.z, vreg.w);
  };

  kv_issue(0, 0);
  v_commit(0);
  __syncthreads();
  int buf = 0;

  const int NT = SEQ / 64;
  for (int kt = 0; kt < NT; ++kt) {
    if (kt + 1 < NT) kv_issue(buf ^ 1, kt + 1);  // loads in flight over compute

    // ---- S^T = K @ Q^T : 4 key-subtiles x 2 q-subtiles, d-depth 64
    f32x4 st[2][4];
    __builtin_amdgcn_s_setprio(1);
#pragma unroll
    for (int ct = 0; ct < 4; ++ct) {
      int krow = ct * 16 + l15;
      const char* kbase = (const char*)&Ks[buf][0] + krow * 128;
      half8 kf0 = *(const half8*)(kbase + ((lg * 16) ^ ((krow & 7) << 4)));
      half8 kf1 = *(const half8*)(kbase + ((64 + lg * 16) ^ ((krow & 7) << 4)));
#pragma unroll
      for (int qb2 = 0; qb2 < 2; ++qb2) {
        st[qb2][ct] = __builtin_amdgcn_mfma_f32_16x16x32_f16(kf0, qf[qb2][0], fzero, 0, 0, 0);
        st[qb2][ct] = __builtin_amdgcn_mfma_f32_16x16x32_f16(kf1, qf[qb2][1], st[qb2][ct], 0, 0, 0);
      }
    }
    __builtin_amdgcn_s_setprio(0);

    // ---- softmax (log2 domain). Common path: no cross-lane ops at all.
    half4v pf[2][4];
#pragma unroll
    for (int qb2 = 0; qb2 < 2; ++qb2) {
      float pmax = st[qb2][0][0];
#pragma unroll
      for (int ct = 0; ct < 4; ++ct)
#pragma unroll
        for (int g = 0; g < 4; ++g) pmax = fmaxf(pmax, st[qb2][ct][g]);
      if (!__all(pmax <= mo[qb2] + 8.0f)) {   // rare rescale path
        float gm = fmaxf(pmax, __shfl_xor(pmax, 16));
        gm = fmaxf(gm, __shfl_xor(gm, 32));
        float mn = fmaxf(gm, mo[qb2]);
        float al = exp2f(mo[qb2] - mn);
        ls[qb2] *= al;
#pragma unroll
        for (int dt = 0; dt < 4; ++dt) o[qb2][dt] *= al;
        mo[qb2] = mn;
      }
      float sum = 0.f;
#pragma unroll
      for (int ct = 0; ct < 4; ++ct) {
#pragma unroll
        for (int g = 0; g < 4; ++g) {
          float pv = exp2f(st[qb2][ct][g] - mo[qb2]);  // bounded by 2^8
          sum += pv;
          pf[qb2][ct][g] = (_Float16)pv;
        }
      }
      ls[qb2] += sum;  // per-lane partial; reduced once in epilogue
    }

    // ---- O^T += V @ P : A = Vs b64 frags (shared across qb2), B = P in-reg
    __builtin_amdgcn_s_setprio(1);
#pragma unroll
    for (int ct = 0; ct < 4; ++ct) {
#pragma unroll
      for (int dt = 0; dt < 4; ++dt) {
        int d = dt * 16 + l15;
        half4v vf = *(const half4v*)((const char*)&Vs[buf][0] + d * 128 +
                                     (((ct * 4 + lg) ^ l15) * 8));
        o[0][dt] = __builtin_amdgcn_mfma_f32_16x16x16f16(vf, pf[0][ct], o[0][dt], 0, 0, 0);
        o[1][dt] = __builtin_amdgcn_mfma_f32_16x16x16f16(vf, pf[1][ct], o[1][dt], 0, 0, 0);
      }
    }
    __builtin_amdgcn_s_setprio(0);

    if (kt + 1 < NT) v_commit(buf ^ 1);  // vmcnt wait + 2x ds_write_b64
    __syncthreads();                     // drains K-DMA too
    buf ^= 1;
  }

  // epilogue: lane holds O[q = qb2*16+l15][d = dt*16 + lg*4 + g]
  const int b = bh / NH, h = bh - b * NH;
#pragma unroll
  for (int qb2 = 0; qb2 < 2; ++qb2) {
    float lsum = ls[qb2];
    lsum += __shfl_xor(lsum, 16);
    lsum += __shfl_xor(lsum, 32);
    const float inv = 1.0f / lsum;
    int q = qt * 256 + wave * 32 + qb2 * 16 + l15;
    size_t base = ((size_t)b * SEQ + q) * CDIM + h * HD;
#pragma unroll
    for (int dt = 0; dt < 4; ++dt) {
      half4v ov;
      ov.x = (_Float16)(o[qb2][dt][0] * inv); ov.y = (_Float16)(o[qb2][dt][1] * inv);
      ov.z = (_Float16)(o[qb2][dt][2] * inv); ov.w = (_Float16)(o[qb2][dt][3] * inv);
      *(half4v*)(ob + base + dt * 16 + lg * 4) = ov;
    }
  }
}

// ---------------- launch ----------------
extern "C" void kernel_launch(void* const* d_in, const int* in_sizes, int n_in,
                              void* d_out, int out_size, void* d_ws, size_t ws_size,
                              hipStream_t stream) {
  const float* x      = (const float*)d_in[0];  // [8,2048,768]
  const float* w_qkv  = (const float*)d_in[1];  // [2304,768]
  const float* w_proj = (const float*)d_in[2];  // [768,768]
  const float* b_proj = (const float*)d_in[3];  // [768]
  float* out = (float*)d_out;                   // [8,2048,768] fp32

  const size_t XN = (size_t)8 * SEQ * CDIM;     // 12,582,912
  const size_t WQ = (size_t)3 * CDIM * CDIM;    // 1,769,472
  const size_t WP = (size_t)CDIM * CDIM;        // 589,824

  _Float16* xb    = (_Float16*)d_ws;
  _Float16* wqkvb = xb + XN;
  _Float16* wpb   = wqkvb + WQ;
  _Float16* qb    = wpb + WP;
  _Float16* kb    = qb + XN;
  _Float16* vtb   = kb + XN;
  _Float16* ob    = vtb + XN;

  cvt_f32_f16<<<(int)(XN / 1024), 256, 0, stream>>>(x, xb, (int)XN);
  cvt_f32_f16<<<(int)(WQ / 1024), 256, 0, stream>>>(w_qkv, wqkvb, (int)WQ);
  cvt_f32_f16<<<(int)(WP / 1024), 256, 0, stream>>>(w_proj, wpb, (int)WP);

  // QKV: M=16384, Nf=2304  (grid 18x128 = 2304 blocks, %8==0)
  gemm_f16<0, 18><<<dim3(18, 128), 256, 0, stream>>>(
      xb, wqkvb, qb, kb, vtb, nullptr, nullptr);

  // attention: 8 q-tiles x 96 heads = 768 blocks = exactly 3/CU
  attn_f16<<<dim3(SEQ / 256, 8 * NH), 512, 0, stream>>>(qb, kb, vtb, ob);

  // proj: M=16384, Nf=768  (grid 6x128 = 768 blocks, %8==0)
  gemm_f16<1, 6><<<dim3(6, 128), 256, 0, stream>>>(
      ob, wpb, nullptr, nullptr, nullptr, out, b_proj);
}

// Round 5
// 324.191 us; speedup vs baseline: 2.6205x; 2.6205x over previous
//
#include <hip/hip_runtime.h>

// Problem constants: B=8, N=2048, C=768, H=12, D=64
#define SEQ   2048
#define NH    12
#define HD    64
#define CDIM  768

typedef _Float16 half8  __attribute__((ext_vector_type(8)));
typedef _Float16 half4v __attribute__((ext_vector_type(4)));
typedef float    f32x4  __attribute__((ext_vector_type(4)));

// 0.125 * log2(e): QK^T scores come out in log2 units -> softmax via exp2 (no mul)
#define QSCALE 0.18033688011112042f

__device__ __forceinline__ void load_lds16(const _Float16* g, _Float16* l) {
  __builtin_amdgcn_global_load_lds(
      (const __attribute__((address_space(1))) void*)g,
      (__attribute__((address_space(3))) void*)l, 16, 0, 0);
}

// ---------------- fp32 -> fp16 convert ----------------
__global__ void cvt_f32_f16(const float* __restrict__ in, _Float16* __restrict__ out, int n) {
  int i = (blockIdx.x * 256 + threadIdx.x) * 4;
  if (i >= n) return;
  float4 v = *(const float4*)(in + i);
  half4v o;
  o.x = (_Float16)v.x; o.y = (_Float16)v.y; o.z = (_Float16)v.z; o.w = (_Float16)v.w;
  *(half4v*)(out + i) = o;
}

// ---------------- GEMM: C[r][f] = sum_k A[r][k] * W[f][k] ----------------
// MODE 0: QKV projection epilogue -> scatter q (scaled by 0.125*log2e), k to
//         [B,H,N,D], v to [B,H,D,N].  MODE 1: fp32 out[r][f] + bias[f].
template <int MODE, int GX>
__global__ __launch_bounds__(256, 2) void gemm_f16(
    const _Float16* __restrict__ A, const _Float16* __restrict__ W,
    _Float16* __restrict__ qo, _Float16* __restrict__ ko, _Float16* __restrict__ vo,
    float* __restrict__ out, const float* __restrict__ bias) {
  __shared__ __align__(16) _Float16 As[128 * 64];
  __shared__ __align__(16) _Float16 Bs[128 * 64];

  const int tid  = threadIdx.x;
  const int wave = tid >> 6;
  const int lane = tid & 63;
  const int wm = wave >> 1, wn = wave & 1;
  const int l15 = lane & 15, lg = lane >> 4;

  // XCD-chunked swizzle (nwg % 8 == 0 for both launches)
  const int nwg = GX * gridDim.y;
  int id = blockIdx.y * GX + blockIdx.x;
  id = (id & 7) * (nwg >> 3) + (id >> 3);
  const int rowBase = (id / GX) * 128;
  const int colBase = (id % GX) * 128;

  const f32x4 fzero = {0.f, 0.f, 0.f, 0.f};
  f32x4 acc[4][4];
#pragma unroll
  for (int m = 0; m < 4; ++m)
#pragma unroll
    for (int n = 0; n < 4; ++n) acc[m][n] = fzero;

  for (int kt = 0; kt < CDIM; kt += 64) {
    __syncthreads();
#pragma unroll
    for (int p = 0; p < 4; ++p) {
      int c = tid + p * 256;
      int r = c >> 3, cb = (c & 7) * 8;  // 8 chunks of 16B per 64-elem row
      load_lds16(A + (size_t)(rowBase + r) * CDIM + kt + cb, As + c * 8);
      load_lds16(W + (size_t)(colBase + r) * CDIM + kt + cb, Bs + c * 8);
    }
    __syncthreads();
#pragma unroll
    for (int ks = 0; ks < 2; ++ks) {
      half8 af[4], bf[4];
#pragma unroll
      for (int m = 0; m < 4; ++m)
        af[m] = *(const half8*)(As + (wm * 64 + m * 16 + l15) * 64 + ks * 32 + lg * 8);
#pragma unroll
      for (int n = 0; n < 4; ++n)
        bf[n] = *(const half8*)(Bs + (wn * 64 + n * 16 + l15) * 64 + ks * 32 + lg * 8);
#pragma unroll
      for (int m = 0; m < 4; ++m)
#pragma unroll
        for (int n = 0; n < 4; ++n)
          acc[m][n] = __builtin_amdgcn_mfma_f32_16x16x32_f16(af[m], bf[n], acc[m][n], 0, 0, 0);
    }
  }

  // Epilogue. C/D frag: col = lane&15, row = (lane>>4)*4 + g
  if constexpr (MODE == 0) {
#pragma unroll
    for (int m = 0; m < 4; ++m) {
#pragma unroll
      for (int n = 0; n < 4; ++n) {
        int f = colBase + wn * 64 + n * 16 + l15;      // 0..2303
        int which = f / CDIM;
        int fr = f - which * CDIM;
        int h = fr >> 6, d = fr & 63;
#pragma unroll
        for (int g = 0; g < 4; ++g) {
          int r = rowBase + wm * 64 + m * 16 + lg * 4 + g;  // 0..16383
          int b = r >> 11, nn = r & 2047;
          float v = acc[m][n][g];
          size_t bh = (size_t)(b * NH + h);
          if (which == 0)      qo[(bh * SEQ + nn) * HD + d] = (_Float16)(v * QSCALE);
          else if (which == 1) ko[(bh * SEQ + nn) * HD + d] = (_Float16)v;
          else                 vo[(bh * HD + d) * SEQ + nn] = (_Float16)v;
        }
      }
    }
  } else {
#pragma unroll
    for (int m = 0; m < 4; ++m) {
#pragma unroll
      for (int n = 0; n < 4; ++n) {
        int f = colBase + wn * 64 + n * 16 + l15;
        float bv = bias[f];
#pragma unroll
        for (int g = 0; g < 4; ++g) {
          int r = rowBase + wm * 64 + m * 16 + lg * 4 + g;
          out[(size_t)r * CDIM + f] = acc[m][n][g] + bv;
        }
      }
    }
  }
}

// ---------------- Flash attention ----------------
// Same structure as round 4 (which was CORRECT and conflict-free; it only
// spilled). block = 512 (8 waves), grid = 768. Wave owns 32 q-rows.
// __launch_bounds__(512, 4): reg cap 128/wave -> the ~96-reg allocation fits
// with NO scratch spill (round-4's (512,6) cap of 85 forced ~2.7 GB of
// spill traffic -> 692 us).
__global__ __launch_bounds__(512, 4) void attn_f16(
    const _Float16* __restrict__ qb, const _Float16* __restrict__ kb,
    const _Float16* __restrict__ vt, _Float16* __restrict__ ob) {
  __shared__ __align__(16) _Float16 Ks[2][64 * 64];
  __shared__ __align__(16) _Float16 Vs[2][64 * 64];

  const int tid  = threadIdx.x;
  const int wave = tid >> 6;
  const int lane = tid & 63;
  const int l15 = lane & 15, lg = lane >> 4;

  // XCD-chunked mapping: xcd = i&7 owns 12 heads x all 8 q-tiles
  const int i = blockIdx.y * gridDim.x + blockIdx.x;  // 0..767
  const int w = i >> 3;                               // 0..95
  const int bh = (i & 7) * NH + (w % NH);
  const int qt = w / NH;                              // 0..7

  const _Float16* qp = qb + (size_t)bh * SEQ * HD;
  const _Float16* kp = kb + (size_t)bh * SEQ * HD;
  const _Float16* vp = vt + (size_t)bh * SEQ * HD;  // Vt: [64 d][2048 keys]

  // Q fragments (pre-scaled): B-frag n = l15 = q, k = lg*8+j
  half8 qf[2][2];
#pragma unroll
  for (int qb2 = 0; qb2 < 2; ++qb2) {
    int qrow = qt * 256 + wave * 32 + qb2 * 16 + l15;
    qf[qb2][0] = *(const half8*)(qp + (size_t)qrow * HD + lg * 8);
    qf[qb2][1] = *(const half8*)(qp + (size_t)qrow * HD + 32 + lg * 8);
  }

  const f32x4 fzero = {0.f, 0.f, 0.f, 0.f};
  f32x4 o[2][4];
#pragma unroll
  for (int qb2 = 0; qb2 < 2; ++qb2)
#pragma unroll
    for (int dt = 0; dt < 4; ++dt) o[qb2][dt] = fzero;
  float mo[2] = {-3.0e38f, -3.0e38f}, ls[2] = {0.f, 0.f};

  // staging indices (tid 0..511 covers the full 64x64 tile once);
  // per-lane invariant offsets precomputed (keeps loop body lean)
  const int sr = tid >> 3;            // row (K key-row / V d-row), 0..63
  const int sa = tid & 7;             // 16B chunk index, 0..7
  const size_t kgoff = (size_t)sr * HD + (((sa * 16) ^ ((sr & 7) << 4)) >> 1);
  const size_t vgoff = (size_t)sr * SEQ + sa * 8;
  _Float16* const ksdst = (_Float16*)Ks + (size_t)tid * 8;   // + buf*4096
  char* const vbase = (char*)Vs + sr * 128;                  // + buf*8192
  const int vs0 = ((2 * sa) ^ (sr & 15)) * 8;
  const int vs1 = ((2 * sa + 1) ^ (sr & 15)) * 8;
  uint4 vreg;

  auto kv_issue = [&](int dstBuf, int kt) {
    load_lds16(kp + (size_t)kt * 64 * HD + kgoff, ksdst + dstBuf * 4096);
    vreg = *(const uint4*)(vp + vgoff + kt * 64);
  };
  auto v_commit = [&](int dstBuf) {
    char* base = vbase + dstBuf * 8192;
    *(uint2*)(base + vs0) = make_uint2(vreg.x, vreg.y);
    *(uint2*)(base + vs1) = make_uint2(vreg.z, vreg.w);
  };

  kv_issue(0, 0);
  v_commit(0);
  __syncthreads();
  int buf = 0;

  const int NT = SEQ / 64;
  for (int kt = 0; kt < NT; ++kt) {
    if (kt + 1 < NT) kv_issue(buf ^ 1, kt + 1);  // loads in flight over compute

    // ---- S^T = K @ Q^T : 4 key-subtiles x 2 q-subtiles, d-depth 64
    f32x4 st[2][4];
    __builtin_amdgcn_s_setprio(1);
#pragma unroll
    for (int ct = 0; ct < 4; ++ct) {
      int krow = ct * 16 + l15;
      const char* kbase = (const char*)&Ks[buf][0] + krow * 128;
      half8 kf0 = *(const half8*)(kbase + ((lg * 16) ^ ((krow & 7) << 4)));
      half8 kf1 = *(const half8*)(kbase + ((64 + lg * 16) ^ ((krow & 7) << 4)));
#pragma unroll
      for (int qb2 = 0; qb2 < 2; ++qb2) {
        st[qb2][ct] = __builtin_amdgcn_mfma_f32_16x16x32_f16(kf0, qf[qb2][0], fzero, 0, 0, 0);
        st[qb2][ct] = __builtin_amdgcn_mfma_f32_16x16x32_f16(kf1, qf[qb2][1], st[qb2][ct], 0, 0, 0);
      }
    }
    __builtin_amdgcn_s_setprio(0);

    // ---- softmax (log2 domain). Common path: no cross-lane ops at all.
    half4v pf[2][4];
#pragma unroll
    for (int qb2 = 0; qb2 < 2; ++qb2) {
      float pmax = st[qb2][0][0];
#pragma unroll
      for (int ct = 0; ct < 4; ++ct)
#pragma unroll
        for (int g = 0; g < 4; ++g) pmax = fmaxf(pmax, st[qb2][ct][g]);
      if (!__all(pmax <= mo[qb2] + 8.0f)) {   // rare rescale path
        float gm = fmaxf(pmax, __shfl_xor(pmax, 16));
        gm = fmaxf(gm, __shfl_xor(gm, 32));
        float mn = fmaxf(gm, mo[qb2]);
        float al = exp2f(mo[qb2] - mn);
        ls[qb2] *= al;
#pragma unroll
        for (int dt = 0; dt < 4; ++dt) o[qb2][dt] *= al;
        mo[qb2] = mn;
      }
      float sum = 0.f;
#pragma unroll
      for (int ct = 0; ct < 4; ++ct) {
#pragma unroll
        for (int g = 0; g < 4; ++g) {
          float pv = exp2f(st[qb2][ct][g] - mo[qb2]);  // bounded by 2^8
          sum += pv;
          pf[qb2][ct][g] = (_Float16)pv;
        }
      }
      ls[qb2] += sum;  // per-lane partial; reduced once in epilogue
    }

    // ---- O^T += V @ P : A = Vs b64 frags (shared across qb2), B = P in-reg
    __builtin_amdgcn_s_setprio(1);
#pragma unroll
    for (int ct = 0; ct < 4; ++ct) {
#pragma unroll
      for (int dt = 0; dt < 4; ++dt) {
        int d = dt * 16 + l15;
        half4v vf = *(const half4v*)((const char*)&Vs[buf][0] + d * 128 +
                                     (((ct * 4 + lg) ^ l15) * 8));
        o[0][dt] = __builtin_amdgcn_mfma_f32_16x16x16f16(vf, pf[0][ct], o[0][dt], 0, 0, 0);
        o[1][dt] = __builtin_amdgcn_mfma_f32_16x16x16f16(vf, pf[1][ct], o[1][dt], 0, 0, 0);
      }
    }
    __builtin_amdgcn_s_setprio(0);

    if (kt + 1 < NT) v_commit(buf ^ 1);  // vmcnt wait + 2x ds_write_b64
    __syncthreads();                     // drains K-DMA too
    buf ^= 1;
  }

  // epilogue: lane holds O[q = qb2*16+l15][d = dt*16 + lg*4 + g]
  const int b = bh / NH, h = bh - b * NH;
#pragma unroll
  for (int qb2 = 0; qb2 < 2; ++qb2) {
    float lsum = ls[qb2];
    lsum += __shfl_xor(lsum, 16);
    lsum += __shfl_xor(lsum, 32);
    const float inv = 1.0f / lsum;
    int q = qt * 256 + wave * 32 + qb2 * 16 + l15;
    size_t base = ((size_t)b * SEQ + q) * CDIM + h * HD;
#pragma unroll
    for (int dt = 0; dt < 4; ++dt) {
      half4v ov;
      ov.x = (_Float16)(o[qb2][dt][0] * inv); ov.y = (_Float16)(o[qb2][dt][1] * inv);
      ov.z = (_Float16)(o[qb2][dt][2] * inv); ov.w = (_Float16)(o[qb2][dt][3] * inv);
      *(half4v*)(ob + base + dt * 16 + lg * 4) = ov;
    }
  }
}

// ---------------- launch ----------------
extern "C" void kernel_launch(void* const* d_in, const int* in_sizes, int n_in,
                              void* d_out, int out_size, void* d_ws, size_t ws_size,
                              hipStream_t stream) {
  const float* x      = (const float*)d_in[0];  // [8,2048,768]
  const float* w_qkv  = (const float*)d_in[1];  // [2304,768]
  const float* w_proj = (const float*)d_in[2];  // [768,768]
  const float* b_proj = (const float*)d_in[3];  // [768]
  float* out = (float*)d_out;                   // [8,2048,768] fp32

  const size_t XN = (size_t)8 * SEQ * CDIM;     // 12,582,912
  const size_t WQ = (size_t)3 * CDIM * CDIM;    // 1,769,472
  const size_t WP = (size_t)CDIM * CDIM;        // 589,824

  _Float16* xb    = (_Float16*)d_ws;
  _Float16* wqkvb = xb + XN;
  _Float16* wpb   = wqkvb + WQ;
  _Float16* qb    = wpb + WP;
  _Float16* kb    = qb + XN;
  _Float16* vtb   = kb + XN;
  _Float16* ob    = vtb + XN;

  cvt_f32_f16<<<(int)(XN / 1024), 256, 0, stream>>>(x, xb, (int)XN);
  cvt_f32_f16<<<(int)(WQ / 1024), 256, 0, stream>>>(w_qkv, wqkvb, (int)WQ);
  cvt_f32_f16<<<(int)(WP / 1024), 256, 0, stream>>>(w_proj, wpb, (int)WP);

  // QKV: M=16384, Nf=2304  (grid 18x128 = 2304 blocks, %8==0)
  gemm_f16<0, 18><<<dim3(18, 128), 256, 0, stream>>>(
      xb, wqkvb, qb, kb, vtb, nullptr, nullptr);

  // attention: 8 q-tiles x 96 heads = 768 blocks
  attn_f16<<<dim3(SEQ / 256, 8 * NH), 512, 0, stream>>>(qb, kb, vtb, ob);

  // proj: M=16384, Nf=768  (grid 6x128 = 768 blocks, %8==0)
  gemm_f16<1, 6><<<dim3(6, 128), 256, 0, stream>>>(
      ob, wpb, nullptr, nullptr, nullptr, out, b_proj);
}

// Round 6
// 291.948 us; speedup vs baseline: 2.9099x; 1.1104x over previous
//
#include <hip/hip_runtime.h>

// Problem constants: B=8, N=2048, C=768, H=12, D=64
#define SEQ   2048
#define NH    12
#define HD    64
#define CDIM  768

typedef _Float16 half8  __attribute__((ext_vector_type(8)));
typedef _Float16 half4v __attribute__((ext_vector_type(4)));
typedef float    f32x4  __attribute__((ext_vector_type(4)));

// 0.125 * log2(e): QK^T scores come out in log2 units -> softmax via exp2 (no mul)
#define QSCALE 0.18033688011112042f

__device__ __forceinline__ void load_lds16(const _Float16* g, _Float16* l) {
  __builtin_amdgcn_global_load_lds(
      (const __attribute__((address_space(1))) void*)g,
      (__attribute__((address_space(3))) void*)l, 16, 0, 0);
}

// ---------------- fp32 -> fp16 convert ----------------
__global__ void cvt_f32_f16(const float* __restrict__ in, _Float16* __restrict__ out, int n) {
  int i = (blockIdx.x * 256 + threadIdx.x) * 4;
  if (i >= n) return;
  float4 v = *(const float4*)(in + i);
  half4v o;
  o.x = (_Float16)v.x; o.y = (_Float16)v.y; o.z = (_Float16)v.z; o.w = (_Float16)v.w;
  *(half4v*)(out + i) = o;
}

// ---------------- GEMM: C[r][f] = sum_k A[r][k] * W[f][k] ----------------
// MODE 0: QKV projection epilogue -> scatter q (scaled by 0.125*log2e), k to
//         [B,H,N,D], v to [B,H,D,N].  MODE 1: fp32 out[r][f] + bias[f].
template <int MODE, int GX>
__global__ __launch_bounds__(256, 2) void gemm_f16(
    const _Float16* __restrict__ A, const _Float16* __restrict__ W,
    _Float16* __restrict__ qo, _Float16* __restrict__ ko, _Float16* __restrict__ vo,
    float* __restrict__ out, const float* __restrict__ bias) {
  __shared__ __align__(16) _Float16 As[128 * 64];
  __shared__ __align__(16) _Float16 Bs[128 * 64];

  const int tid  = threadIdx.x;
  const int wave = tid >> 6;
  const int lane = tid & 63;
  const int wm = wave >> 1, wn = wave & 1;
  const int l15 = lane & 15, lg = lane >> 4;

  // XCD-chunked swizzle (nwg % 8 == 0 for both launches)
  const int nwg = GX * gridDim.y;
  int id = blockIdx.y * GX + blockIdx.x;
  id = (id & 7) * (nwg >> 3) + (id >> 3);
  const int rowBase = (id / GX) * 128;
  const int colBase = (id % GX) * 128;

  const f32x4 fzero = {0.f, 0.f, 0.f, 0.f};
  f32x4 acc[4][4];
#pragma unroll
  for (int m = 0; m < 4; ++m)
#pragma unroll
    for (int n = 0; n < 4; ++n) acc[m][n] = fzero;

  for (int kt = 0; kt < CDIM; kt += 64) {
    __syncthreads();
#pragma unroll
    for (int p = 0; p < 4; ++p) {
      int c = tid + p * 256;
      int r = c >> 3, cb = (c & 7) * 8;  // 8 chunks of 16B per 64-elem row
      load_lds16(A + (size_t)(rowBase + r) * CDIM + kt + cb, As + c * 8);
      load_lds16(W + (size_t)(colBase + r) * CDIM + kt + cb, Bs + c * 8);
    }
    __syncthreads();
#pragma unroll
    for (int ks = 0; ks < 2; ++ks) {
      half8 af[4], bf[4];
#pragma unroll
      for (int m = 0; m < 4; ++m)
        af[m] = *(const half8*)(As + (wm * 64 + m * 16 + l15) * 64 + ks * 32 + lg * 8);
#pragma unroll
      for (int n = 0; n < 4; ++n)
        bf[n] = *(const half8*)(Bs + (wn * 64 + n * 16 + l15) * 64 + ks * 32 + lg * 8);
#pragma unroll
      for (int m = 0; m < 4; ++m)
#pragma unroll
        for (int n = 0; n < 4; ++n)
          acc[m][n] = __builtin_amdgcn_mfma_f32_16x16x32_f16(af[m], bf[n], acc[m][n], 0, 0, 0);
    }
  }

  // Epilogue. C/D frag: col = lane&15, row = (lane>>4)*4 + g
  if constexpr (MODE == 0) {
#pragma unroll
    for (int m = 0; m < 4; ++m) {
#pragma unroll
      for (int n = 0; n < 4; ++n) {
        int f = colBase + wn * 64 + n * 16 + l15;      // 0..2303
        int which = f / CDIM;
        int fr = f - which * CDIM;
        int h = fr >> 6, d = fr & 63;
#pragma unroll
        for (int g = 0; g < 4; ++g) {
          int r = rowBase + wm * 64 + m * 16 + lg * 4 + g;  // 0..16383
          int b = r >> 11, nn = r & 2047;
          float v = acc[m][n][g];
          size_t bh = (size_t)(b * NH + h);
          if (which == 0)      qo[(bh * SEQ + nn) * HD + d] = (_Float16)(v * QSCALE);
          else if (which == 1) ko[(bh * SEQ + nn) * HD + d] = (_Float16)v;
          else                 vo[(bh * HD + d) * SEQ + nn] = (_Float16)v;
        }
      }
    }
  } else {
#pragma unroll
    for (int m = 0; m < 4; ++m) {
#pragma unroll
      for (int n = 0; n < 4; ++n) {
        int f = colBase + wn * 64 + n * 16 + l15;
        float bv = bias[f];
#pragma unroll
        for (int g = 0; g < 4; ++g) {
          int r = rowBase + wm * 64 + m * 16 + lg * 4 + g;
          out[(size_t)r * CDIM + f] = acc[m][n][g] + bv;
        }
      }
    }
  }
}

// ---------------- Flash attention ----------------
// block = 512 (8 waves), grid = 768. Wave owns 32 q-rows; lane owns 2 queries.
// VALU-lean softmax:
//  - QK MFMA C-init = -mo (per-lane = per-query)  -> subtraction is free
//  - row-sum via ones-MFMA (complete 64-key sum)  -> no VALU adds, no fmax,
//    no epilogue shuffle reduce; ls is exact
//  - overflow detection on the SUM (sum<=4096 => every pv<=4096, f16-safe;
//    inf/NaN fail the compare) -> rare fixup path recomputes with true max
//    BEFORE PV touches o.  mo init = 0 (no -inf blowup).
//  - raw v_exp_f32 via __builtin_amdgcn_exp2f (no OCML denorm guard;
//    flush-to-zero below 2^-126 is exactly softmax semantics)
__global__ __launch_bounds__(512, 4) void attn_f16(
    const _Float16* __restrict__ qb, const _Float16* __restrict__ kb,
    const _Float16* __restrict__ vt, _Float16* __restrict__ ob) {
  __shared__ __align__(16) _Float16 Ks[2][64 * 64];
  __shared__ __align__(16) _Float16 Vs[2][64 * 64];

  const int tid  = threadIdx.x;
  const int wave = tid >> 6;
  const int lane = tid & 63;
  const int l15 = lane & 15, lg = lane >> 4;

  // XCD-chunked mapping: xcd = i&7 owns 12 heads x all 8 q-tiles
  const int i = blockIdx.y * gridDim.x + blockIdx.x;  // 0..767
  const int w = i >> 3;                               // 0..95
  const int bh = (i & 7) * NH + (w % NH);
  const int qt = w / NH;                              // 0..7

  const _Float16* qp = qb + (size_t)bh * SEQ * HD;
  const _Float16* kp = kb + (size_t)bh * SEQ * HD;
  const _Float16* vp = vt + (size_t)bh * SEQ * HD;  // Vt: [64 d][2048 keys]

  // Q fragments (pre-scaled): B-frag n = l15 = q, k = lg*8+j
  half8 qf[2][2];
#pragma unroll
  for (int qb2 = 0; qb2 < 2; ++qb2) {
    int qrow = qt * 256 + wave * 32 + qb2 * 16 + l15;
    qf[qb2][0] = *(const half8*)(qp + (size_t)qrow * HD + lg * 8);
    qf[qb2][1] = *(const half8*)(qp + (size_t)qrow * HD + 32 + lg * 8);
  }

  const f32x4 fzero = {0.f, 0.f, 0.f, 0.f};
  const half4v onesv = {(_Float16)1.f, (_Float16)1.f, (_Float16)1.f, (_Float16)1.f};
  f32x4 o[2][4];
#pragma unroll
  for (int qb2 = 0; qb2 < 2; ++qb2)
#pragma unroll
    for (int dt = 0; dt < 4; ++dt) o[qb2][dt] = fzero;
  f32x4 minit[2] = {fzero, fzero};   // = -mo (log2 units), per-query
  float ls[2] = {0.f, 0.f};          // exact per-query sum

  // staging indices (tid 0..511 covers the full 64x64 tile once)
  const int sr = tid >> 3;            // row (K key-row / V d-row), 0..63
  const int sa = tid & 7;             // 16B chunk index, 0..7
  const size_t kgoff = (size_t)sr * HD + (((sa * 16) ^ ((sr & 7) << 4)) >> 1);
  const size_t vgoff = (size_t)sr * SEQ + sa * 8;
  _Float16* const ksdst = (_Float16*)Ks + (size_t)tid * 8;   // + buf*4096
  char* const vbase = (char*)Vs + sr * 128;                  // + buf*8192
  const int vs0 = ((2 * sa) ^ (sr & 15)) * 8;
  const int vs1 = ((2 * sa + 1) ^ (sr & 15)) * 8;
  uint4 vreg;

  auto kv_issue = [&](int dstBuf, int kt) {
    load_lds16(kp + (size_t)kt * 64 * HD + kgoff, ksdst + dstBuf * 4096);
    vreg = *(const uint4*)(vp + vgoff + kt * 64);
  };
  auto v_commit = [&](int dstBuf) {
    char* base = vbase + dstBuf * 8192;
    *(uint2*)(base + vs0) = make_uint2(vreg.x, vreg.y);
    *(uint2*)(base + vs1) = make_uint2(vreg.z, vreg.w);
  };

  kv_issue(0, 0);
  v_commit(0);
  __syncthreads();
  int buf = 0;

  const float TH = 4096.0f;  // defer window 2^12; pv <= sum <= TH fits f16
  const int NT = SEQ / 64;
  for (int kt = 0; kt < NT; ++kt) {
    if (kt + 1 < NT) kv_issue(buf ^ 1, kt + 1);  // loads in flight over compute

    // ---- S^T - mo = K @ Q^T + (-mo) : C-init carries the softmax shift
    f32x4 st[2][4];
    __builtin_amdgcn_s_setprio(1);
#pragma unroll
    for (int ct = 0; ct < 4; ++ct) {
      int krow = ct * 16 + l15;
      const char* kbase = (const char*)&Ks[buf][0] + krow * 128;
      half8 kf0 = *(const half8*)(kbase + ((lg * 16) ^ ((krow & 7) << 4)));
      half8 kf1 = *(const half8*)(kbase + ((64 + lg * 16) ^ ((krow & 7) << 4)));
#pragma unroll
      for (int qb2 = 0; qb2 < 2; ++qb2) {
        st[qb2][ct] = __builtin_amdgcn_mfma_f32_16x16x32_f16(kf0, qf[qb2][0], minit[qb2], 0, 0, 0);
        st[qb2][ct] = __builtin_amdgcn_mfma_f32_16x16x32_f16(kf1, qf[qb2][1], st[qb2][ct], 0, 0, 0);
      }
    }
    __builtin_amdgcn_s_setprio(0);

    // ---- P = exp2(st); complete row-sum via ones-MFMA
    half4v pf[2][4];
    f32x4 osum[2];
#pragma unroll
    for (int qb2 = 0; qb2 < 2; ++qb2) {
#pragma unroll
      for (int ct = 0; ct < 4; ++ct)
#pragma unroll
        for (int g = 0; g < 4; ++g)
          pf[qb2][ct][g] = (_Float16)__builtin_amdgcn_exp2f(st[qb2][ct][g]);
      osum[qb2] = fzero;
#pragma unroll
      for (int ct = 0; ct < 4; ++ct)
        osum[qb2] = __builtin_amdgcn_mfma_f32_16x16x16f16(onesv, pf[qb2][ct], osum[qb2], 0, 0, 0);
    }

    // ---- overflow check on the sum (inf/NaN fail the <=) -> rare fixup
    if (!__all((osum[0][0] <= TH) && (osum[1][0] <= TH))) {
#pragma unroll
      for (int qb2 = 0; qb2 < 2; ++qb2) {
        float gm = st[qb2][0][0];
#pragma unroll
        for (int ct = 0; ct < 4; ++ct)
#pragma unroll
          for (int g = 0; g < 4; ++g) gm = fmaxf(gm, st[qb2][ct][g]);
        gm = fmaxf(gm, __shfl_xor(gm, 16));
        gm = fmaxf(gm, __shfl_xor(gm, 32));
        float d = fmaxf(gm, 0.0f);                    // shift so new max -> 0
        float al = __builtin_amdgcn_exp2f(-d);
        ls[qb2] *= al;
#pragma unroll
        for (int dt = 0; dt < 4; ++dt) o[qb2][dt] *= al;
        minit[qb2] = minit[qb2] - d;
#pragma unroll
        for (int ct = 0; ct < 4; ++ct)
#pragma unroll
          for (int g = 0; g < 4; ++g)
            pf[qb2][ct][g] = (_Float16)__builtin_amdgcn_exp2f(st[qb2][ct][g] - d);
        osum[qb2] = fzero;
#pragma unroll
        for (int ct = 0; ct < 4; ++ct)
          osum[qb2] = __builtin_amdgcn_mfma_f32_16x16x16f16(onesv, pf[qb2][ct], osum[qb2], 0, 0, 0);
      }
    }
    ls[0] += osum[0][0];
    ls[1] += osum[1][0];

    // ---- O^T += V @ P : A = Vs b64 frags (shared across qb2), B = P in-reg
    __builtin_amdgcn_s_setprio(1);
#pragma unroll
    for (int ct = 0; ct < 4; ++ct) {
#pragma unroll
      for (int dt = 0; dt < 4; ++dt) {
        int d = dt * 16 + l15;
        half4v vf = *(const half4v*)((const char*)&Vs[buf][0] + d * 128 +
                                     (((ct * 4 + lg) ^ l15) * 8));
        o[0][dt] = __builtin_amdgcn_mfma_f32_16x16x16f16(vf, pf[0][ct], o[0][dt], 0, 0, 0);
        o[1][dt] = __builtin_amdgcn_mfma_f32_16x16x16f16(vf, pf[1][ct], o[1][dt], 0, 0, 0);
      }
    }
    __builtin_amdgcn_s_setprio(0);

    if (kt + 1 < NT) v_commit(buf ^ 1);  // vmcnt wait + 2x ds_write_b64
    __syncthreads();                     // drains K-DMA too
    buf ^= 1;
  }

  // epilogue: lane holds O[q = qb2*16+l15][d = dt*16 + lg*4 + g]; ls is exact
  const int b = bh / NH, h = bh - b * NH;
#pragma unroll
  for (int qb2 = 0; qb2 < 2; ++qb2) {
    const float inv = 1.0f / ls[qb2];
    int q = qt * 256 + wave * 32 + qb2 * 16 + l15;
    size_t base = ((size_t)b * SEQ + q) * CDIM + h * HD;
#pragma unroll
    for (int dt = 0; dt < 4; ++dt) {
      half4v ov;
      ov.x = (_Float16)(o[qb2][dt][0] * inv); ov.y = (_Float16)(o[qb2][dt][1] * inv);
      ov.z = (_Float16)(o[qb2][dt][2] * inv); ov.w = (_Float16)(o[qb2][dt][3] * inv);
      *(half4v*)(ob + base + dt * 16 + lg * 4) = ov;
    }
  }
}

// ---------------- launch ----------------
extern "C" void kernel_launch(void* const* d_in, const int* in_sizes, int n_in,
                              void* d_out, int out_size, void* d_ws, size_t ws_size,
                              hipStream_t stream) {
  const float* x      = (const float*)d_in[0];  // [8,2048,768]
  const float* w_qkv  = (const float*)d_in[1];  // [2304,768]
  const float* w_proj = (const float*)d_in[2];  // [768,768]
  const float* b_proj = (const float*)d_in[3];  // [768]
  float* out = (float*)d_out;                   // [8,2048,768] fp32

  const size_t XN = (size_t)8 * SEQ * CDIM;     // 12,582,912
  const size_t WQ = (size_t)3 * CDIM * CDIM;    // 1,769,472
  const size_t WP = (size_t)CDIM * CDIM;        // 589,824

  _Float16* xb    = (_Float16*)d_ws;
  _Float16* wqkvb = xb + XN;
  _Float16* wpb   = wqkvb + WQ;
  _Float16* qb    = wpb + WP;
  _Float16* kb    = qb + XN;
  _Float16* vtb   = kb + XN;
  _Float16* ob    = vtb + XN;

  cvt_f32_f16<<<(int)(XN / 1024), 256, 0, stream>>>(x, xb, (int)XN);
  cvt_f32_f16<<<(int)(WQ / 1024), 256, 0, stream>>>(w_qkv, wqkvb, (int)WQ);
  cvt_f32_f16<<<(int)(WP / 1024), 256, 0, stream>>>(w_proj, wpb, (int)WP);

  // QKV: M=16384, Nf=2304  (grid 18x128 = 2304 blocks, %8==0)
  gemm_f16<0, 18><<<dim3(18, 128), 256, 0, stream>>>(
      xb, wqkvb, qb, kb, vtb, nullptr, nullptr);

  // attention: 8 q-tiles x 96 heads = 768 blocks
  attn_f16<<<dim3(SEQ / 256, 8 * NH), 512, 0, stream>>>(qb, kb, vtb, ob);

  // proj: M=16384, Nf=768  (grid 6x128 = 768 blocks, %8==0)
  gemm_f16<1, 6><<<dim3(6, 128), 256, 0, stream>>>(
      ob, wpb, nullptr, nullptr, nullptr, out, b_proj);
}

// Round 7
// 255.720 us; speedup vs baseline: 3.3222x; 1.1417x over previous
//
#include <hip/hip_runtime.h>

// Problem constants: B=8, N=2048, C=768, H=12, D=64
#define SEQ   2048
#define NH    12
#define HD    64
#define CDIM  768

typedef _Float16 half8  __attribute__((ext_vector_type(8)));
typedef _Float16 half4v __attribute__((ext_vector_type(4)));
typedef float    f32x4  __attribute__((ext_vector_type(4)));

// 0.125 * log2(e): QK^T scores come out in log2 units -> softmax via exp2 (no mul)
#define QSCALE 0.18033688011112042f

__device__ __forceinline__ void load_lds16(const _Float16* g, _Float16* l) {
  __builtin_amdgcn_global_load_lds(
      (const __attribute__((address_space(1))) void*)g,
      (__attribute__((address_space(3))) void*)l, 16, 0, 0);
}

// ---------------- fp32 -> fp16 convert ----------------
__global__ void cvt_f32_f16(const float* __restrict__ in, _Float16* __restrict__ out, int n) {
  int i = (blockIdx.x * 256 + threadIdx.x) * 4;
  if (i >= n) return;
  float4 v = *(const float4*)(in + i);
  half4v o;
  o.x = (_Float16)v.x; o.y = (_Float16)v.y; o.z = (_Float16)v.z; o.w = (_Float16)v.w;
  *(half4v*)(out + i) = o;
}

// ---------------- GEMM: C[r][f] = sum_k A[r][k] * W[f][k] ----------------
// MODE 0: QKV projection epilogue -> scatter q (scaled by 0.125*log2e), k to
//         [B,H,N,D], v to [B,H,D,N].  MODE 1: fp32 out[r][f] + bias[f].
template <int MODE, int GX>
__global__ __launch_bounds__(256, 2) void gemm_f16(
    const _Float16* __restrict__ A, const _Float16* __restrict__ W,
    _Float16* __restrict__ qo, _Float16* __restrict__ ko, _Float16* __restrict__ vo,
    float* __restrict__ out, const float* __restrict__ bias) {
  __shared__ __align__(16) _Float16 As[128 * 64];
  __shared__ __align__(16) _Float16 Bs[128 * 64];

  const int tid  = threadIdx.x;
  const int wave = tid >> 6;
  const int lane = tid & 63;
  const int wm = wave >> 1, wn = wave & 1;
  const int l15 = lane & 15, lg = lane >> 4;

  // XCD-chunked swizzle (nwg % 8 == 0 for both launches)
  const int nwg = GX * gridDim.y;
  int id = blockIdx.y * GX + blockIdx.x;
  id = (id & 7) * (nwg >> 3) + (id >> 3);
  const int rowBase = (id / GX) * 128;
  const int colBase = (id % GX) * 128;

  const f32x4 fzero = {0.f, 0.f, 0.f, 0.f};
  f32x4 acc[4][4];
#pragma unroll
  for (int m = 0; m < 4; ++m)
#pragma unroll
    for (int n = 0; n < 4; ++n) acc[m][n] = fzero;

  for (int kt = 0; kt < CDIM; kt += 64) {
    __syncthreads();
#pragma unroll
    for (int p = 0; p < 4; ++p) {
      int c = tid + p * 256;
      int r = c >> 3, cb = (c & 7) * 8;  // 8 chunks of 16B per 64-elem row
      load_lds16(A + (size_t)(rowBase + r) * CDIM + kt + cb, As + c * 8);
      load_lds16(W + (size_t)(colBase + r) * CDIM + kt + cb, Bs + c * 8);
    }
    __syncthreads();
#pragma unroll
    for (int ks = 0; ks < 2; ++ks) {
      half8 af[4], bf[4];
#pragma unroll
      for (int m = 0; m < 4; ++m)
        af[m] = *(const half8*)(As + (wm * 64 + m * 16 + l15) * 64 + ks * 32 + lg * 8);
#pragma unroll
      for (int n = 0; n < 4; ++n)
        bf[n] = *(const half8*)(Bs + (wn * 64 + n * 16 + l15) * 64 + ks * 32 + lg * 8);
#pragma unroll
      for (int m = 0; m < 4; ++m)
#pragma unroll
        for (int n = 0; n < 4; ++n)
          acc[m][n] = __builtin_amdgcn_mfma_f32_16x16x32_f16(af[m], bf[n], acc[m][n], 0, 0, 0);
    }
  }

  // Epilogue. C/D frag: col = lane&15, row = (lane>>4)*4 + g
  if constexpr (MODE == 0) {
#pragma unroll
    for (int m = 0; m < 4; ++m) {
#pragma unroll
      for (int n = 0; n < 4; ++n) {
        int f = colBase + wn * 64 + n * 16 + l15;      // 0..2303
        int which = f / CDIM;                          // uniform per (m,n)
        int fr = f - which * CDIM;
        int h = fr >> 6, d = fr & 63;
        int r0 = rowBase + wm * 64 + m * 16 + lg * 4;  // 4 consecutive rows
        int b = r0 >> 11, nn = r0 & 2047;              // never crosses 2048
        size_t bh = (size_t)(b * NH + h);
        if (which == 2) {
          // v: [B,H,D,N] -> the 4 g-values are consecutive n -> one 8B store
          half4v vv;
#pragma unroll
          for (int g = 0; g < 4; ++g) vv[g] = (_Float16)acc[m][n][g];
          *(half4v*)(vo + ((bh * HD + d) * SEQ + nn)) = vv;
        } else {
#pragma unroll
          for (int g = 0; g < 4; ++g) {
            float v = acc[m][n][g];
            if (which == 0) qo[(bh * SEQ + nn + g) * HD + d] = (_Float16)(v * QSCALE);
            else            ko[(bh * SEQ + nn + g) * HD + d] = (_Float16)v;
          }
        }
      }
    }
  } else {
#pragma unroll
    for (int m = 0; m < 4; ++m) {
#pragma unroll
      for (int n = 0; n < 4; ++n) {
        int f = colBase + wn * 64 + n * 16 + l15;
        float bv = bias[f];
#pragma unroll
        for (int g = 0; g < 4; ++g) {
          int r = rowBase + wm * 64 + m * 16 + lg * 4 + g;
          out[(size_t)r * CDIM + f] = acc[m][n][g] + bv;
        }
      }
    }
  }
}

// ---------------- Flash attention ----------------
// block = 512 (8 waves), grid = 768. Wave owns 32 q-rows; lane owns 2 queries.
// KEY-PERMUTED K staging: LDS K row (t*16+m) holds global key
//   (t>>1)*32 + (m>>2)*8 + (t&1)*4 + (m&3),
// so S tile t's C-frag (row = lg*4+g) gives lane the scores for keys
//   kb*32 + lg*8 + (t&1)*4 + g   (kb = t>>1).
// => concat(exp(st[2kb]), exp(st[2kb+1])) IS the 16x16x32 B-frag (k=lg*8+j)
//    for PV -> PV runs as 16 x mfma_16x16x32 with V read as ds_read_b128.
// V LDS: [64 d][72 halfs] (144B row stride spreads banks; <=2-way = free),
// keys stored LINEAR (match P's global-key indexing). V commit = 1 b128 write.
// Softmax: C-init = -mo, ones-MFMA row sum, sum-overflow defer check, raw exp2.
__global__ __launch_bounds__(512, 4) void attn_f16(
    const _Float16* __restrict__ qb, const _Float16* __restrict__ kb,
    const _Float16* __restrict__ vt, _Float16* __restrict__ ob) {
  __shared__ __align__(16) _Float16 Ks[2][64 * 64];
  __shared__ __align__(16) _Float16 Vs[2][64 * 72];

  const int tid  = threadIdx.x;
  const int wave = tid >> 6;
  const int lane = tid & 63;
  const int l15 = lane & 15, lg = lane >> 4;

  // XCD-chunked mapping: xcd = i&7 owns 12 heads x all 8 q-tiles
  const int i = blockIdx.y * gridDim.x + blockIdx.x;  // 0..767
  const int w = i >> 3;                               // 0..95
  const int bh = (i & 7) * NH + (w % NH);
  const int qt = w / NH;                              // 0..7

  const _Float16* qp = qb + (size_t)bh * SEQ * HD;
  const _Float16* kp = kb + (size_t)bh * SEQ * HD;
  const _Float16* vp = vt + (size_t)bh * SEQ * HD;  // Vt: [64 d][2048 keys]

  // Q fragments (pre-scaled): B-frag n = l15 = q, k = lg*8+j
  half8 qf[2][2];
#pragma unroll
  for (int qb2 = 0; qb2 < 2; ++qb2) {
    int qrow = qt * 256 + wave * 32 + qb2 * 16 + l15;
    qf[qb2][0] = *(const half8*)(qp + (size_t)qrow * HD + lg * 8);
    qf[qb2][1] = *(const half8*)(qp + (size_t)qrow * HD + 32 + lg * 8);
  }

  const f32x4 fzero = {0.f, 0.f, 0.f, 0.f};
  const _Float16 h1 = (_Float16)1.f;
  const half8 ones8 = {h1, h1, h1, h1, h1, h1, h1, h1};
  f32x4 o[2][4];
#pragma unroll
  for (int qb2 = 0; qb2 < 2; ++qb2)
#pragma unroll
    for (int dt = 0; dt < 4; ++dt) o[qb2][dt] = fzero;
  f32x4 minit[2] = {fzero, fzero};   // = -mo (log2 units), per-query
  float ls[2] = {0.f, 0.f};          // exact per-query sum

  // staging indices (tid 0..511 covers each 64-row tile once)
  const int sr = tid >> 3;            // LDS row (K) / d-row (V), 0..63
  const int sa = tid & 7;             // 16B chunk index, 0..7
  // K row permutation: LDS row sr <- global key kperm(sr)
  const int kt_ = sr >> 4, km = sr & 15;
  const int kperm = ((kt_ >> 1) << 5) + ((km >> 2) << 3) + ((kt_ & 1) << 2) + (km & 3);
  const size_t kgoff = (size_t)kperm * HD + (((sa * 16) ^ ((sr & 7) << 4)) >> 1);
  const size_t vgoff = (size_t)sr * SEQ + sa * 8;            // keys linear
  _Float16* const ksdst = (_Float16*)Ks + (size_t)tid * 8;   // + buf*4096
  _Float16* const vdst  = (_Float16*)Vs + sr * 72 + sa * 8;  // + buf*4608
  uint4 vreg;

  auto kv_issue = [&](int dstBuf, int kt) {
    load_lds16(kp + (size_t)kt * 64 * HD + kgoff, ksdst + dstBuf * 4096);
    vreg = *(const uint4*)(vp + vgoff + kt * 64);
  };
  auto v_commit = [&](int dstBuf) {
    *(uint4*)(vdst + dstBuf * 4608) = vreg;   // single ds_write_b128
  };

  kv_issue(0, 0);
  v_commit(0);
  __syncthreads();
  int buf = 0;

  const float TH = 4096.0f;  // defer window 2^12; pv <= sum <= TH fits f16
  const int NT = SEQ / 64;
  for (int kt = 0; kt < NT; ++kt) {
    if (kt + 1 < NT) kv_issue(buf ^ 1, kt + 1);  // loads in flight over compute

    // ---- S^T - mo = K @ Q^T + (-mo) : C-init carries the softmax shift
    f32x4 st[2][4];
    __builtin_amdgcn_s_setprio(1);
#pragma unroll
    for (int ct = 0; ct < 4; ++ct) {
      int krow = ct * 16 + l15;
      const char* kbase = (const char*)&Ks[buf][0] + krow * 128;
      half8 kf0 = *(const half8*)(kbase + ((lg * 16) ^ ((krow & 7) << 4)));
      half8 kf1 = *(const half8*)(kbase + ((64 + lg * 16) ^ ((krow & 7) << 4)));
#pragma unroll
      for (int qb2 = 0; qb2 < 2; ++qb2) {
        st[qb2][ct] = __builtin_amdgcn_mfma_f32_16x16x32_f16(kf0, qf[qb2][0], minit[qb2], 0, 0, 0);
        st[qb2][ct] = __builtin_amdgcn_mfma_f32_16x16x32_f16(kf1, qf[qb2][1], st[qb2][ct], 0, 0, 0);
      }
    }
    __builtin_amdgcn_s_setprio(0);

    // ---- P = exp2(st), assembled directly as PV B-frags (k = lg*8+j);
    //      complete row-sum via ones-MFMA (16x16x32)
    half8 pvb[2][2];
    f32x4 osum[2];
#pragma unroll
    for (int qb2 = 0; qb2 < 2; ++qb2) {
#pragma unroll
      for (int kbk = 0; kbk < 2; ++kbk)
#pragma unroll
        for (int j = 0; j < 8; ++j)
          pvb[qb2][kbk][j] =
              (_Float16)__builtin_amdgcn_exp2f(st[qb2][2 * kbk + (j >> 2)][j & 3]);
      osum[qb2] = __builtin_amdgcn_mfma_f32_16x16x32_f16(ones8, pvb[qb2][0], fzero, 0, 0, 0);
      osum[qb2] = __builtin_amdgcn_mfma_f32_16x16x32_f16(ones8, pvb[qb2][1], osum[qb2], 0, 0, 0);
    }

    // ---- overflow check on the sum (inf/NaN fail the <=) -> rare fixup
    if (!__all((osum[0][0] <= TH) && (osum[1][0] <= TH))) {
#pragma unroll
      for (int qb2 = 0; qb2 < 2; ++qb2) {
        float gm = st[qb2][0][0];
#pragma unroll
        for (int ct = 0; ct < 4; ++ct)
#pragma unroll
          for (int g = 0; g < 4; ++g) gm = fmaxf(gm, st[qb2][ct][g]);
        gm = fmaxf(gm, __shfl_xor(gm, 16));
        gm = fmaxf(gm, __shfl_xor(gm, 32));
        float d = fmaxf(gm, 0.0f);                    // shift so new max -> 0
        float al = __builtin_amdgcn_exp2f(-d);
        ls[qb2] *= al;
#pragma unroll
        for (int dt = 0; dt < 4; ++dt) o[qb2][dt] *= al;
        minit[qb2] = minit[qb2] - d;
#pragma unroll
        for (int kbk = 0; kbk < 2; ++kbk)
#pragma unroll
          for (int j = 0; j < 8; ++j)
            pvb[qb2][kbk][j] =
                (_Float16)__builtin_amdgcn_exp2f(st[qb2][2 * kbk + (j >> 2)][j & 3] - d);
        osum[qb2] = __builtin_amdgcn_mfma_f32_16x16x32_f16(ones8, pvb[qb2][0], fzero, 0, 0, 0);
        osum[qb2] = __builtin_amdgcn_mfma_f32_16x16x32_f16(ones8, pvb[qb2][1], osum[qb2], 0, 0, 0);
      }
    }
    ls[0] += osum[0][0];
    ls[1] += osum[1][0];

    // ---- O^T += V @ P : A = V b128 frags [d=l15][k=lg*8+j], B = pvb in-reg
    __builtin_amdgcn_s_setprio(1);
#pragma unroll
    for (int kbk = 0; kbk < 2; ++kbk) {
#pragma unroll
      for (int dt = 0; dt < 4; ++dt) {
        int d = dt * 16 + l15;
        half8 vf = *(const half8*)((const char*)&Vs[buf][0] + d * 144 + kbk * 64 + lg * 16);
        o[0][dt] = __builtin_amdgcn_mfma_f32_16x16x32_f16(vf, pvb[0][kbk], o[0][dt], 0, 0, 0);
        o[1][dt] = __builtin_amdgcn_mfma_f32_16x16x32_f16(vf, pvb[1][kbk], o[1][dt], 0, 0, 0);
      }
    }
    __builtin_amdgcn_s_setprio(0);

    if (kt + 1 < NT) v_commit(buf ^ 1);  // vmcnt wait + 1x ds_write_b128
    __syncthreads();                     // drains K-DMA too
    buf ^= 1;
  }

  // epilogue: lane holds O[q = qb2*16+l15][d = dt*16 + lg*4 + g]; ls is exact
  const int b = bh / NH, h = bh - b * NH;
#pragma unroll
  for (int qb2 = 0; qb2 < 2; ++qb2) {
    const float inv = 1.0f / ls[qb2];
    int q = qt * 256 + wave * 32 + qb2 * 16 + l15;
    size_t base = ((size_t)b * SEQ + q) * CDIM + h * HD;
#pragma unroll
    for (int dt = 0; dt < 4; ++dt) {
      half4v ov;
      ov.x = (_Float16)(o[qb2][dt][0] * inv); ov.y = (_Float16)(o[qb2][dt][1] * inv);
      ov.z = (_Float16)(o[qb2][dt][2] * inv); ov.w = (_Float16)(o[qb2][dt][3] * inv);
      *(half4v*)(ob + base + dt * 16 + lg * 4) = ov;
    }
  }
}

// ---------------- launch ----------------
extern "C" void kernel_launch(void* const* d_in, const int* in_sizes, int n_in,
                              void* d_out, int out_size, void* d_ws, size_t ws_size,
                              hipStream_t stream) {
  const float* x      = (const float*)d_in[0];  // [8,2048,768]
  const float* w_qkv  = (const float*)d_in[1];  // [2304,768]
  const float* w_proj = (const float*)d_in[2];  // [768,768]
  const float* b_proj = (const float*)d_in[3];  // [768]
  float* out = (float*)d_out;                   // [8,2048,768] fp32

  const size_t XN = (size_t)8 * SEQ * CDIM;     // 12,582,912
  const size_t WQ = (size_t)3 * CDIM * CDIM;    // 1,769,472
  const size_t WP = (size_t)CDIM * CDIM;        // 589,824

  _Float16* xb    = (_Float16*)d_ws;
  _Float16* wqkvb = xb + XN;
  _Float16* wpb   = wqkvb + WQ;
  _Float16* qb    = wpb + WP;
  _Float16* kb    = qb + XN;
  _Float16* vtb   = kb + XN;
  _Float16* ob    = vtb + XN;

  cvt_f32_f16<<<(int)(XN / 1024), 256, 0, stream>>>(x, xb, (int)XN);
  cvt_f32_f16<<<(int)(WQ / 1024), 256, 0, stream>>>(w_qkv, wqkvb, (int)WQ);
  cvt_f32_f16<<<(int)(WP / 1024), 256, 0, stream>>>(w_proj, wpb, (int)WP);

  // QKV: M=16384, Nf=2304  (grid 18x128 = 2304 blocks, %8==0)
  gemm_f16<0, 18><<<dim3(18, 128), 256, 0, stream>>>(
      xb, wqkvb, qb, kb, vtb, nullptr, nullptr);

  // attention: 8 q-tiles x 96 heads = 768 blocks
  attn_f16<<<dim3(SEQ / 256, 8 * NH), 512, 0, stream>>>(qb, kb, vtb, ob);

  // proj: M=16384, Nf=768  (grid 6x128 = 768 blocks, %8==0)
  gemm_f16<1, 6><<<dim3(6, 128), 256, 0, stream>>>(
      ob, wpb, nullptr, nullptr, nullptr, out, b_proj);
}

// Round 9
// 248.720 us; speedup vs baseline: 3.4157x; 1.0281x over previous
//
#include <hip/hip_runtime.h>

// Problem constants: B=8, N=2048, C=768, H=12, D=64
#define SEQ   2048
#define NH    12
#define HD    64
#define CDIM  768

typedef _Float16 half8  __attribute__((ext_vector_type(8)));
typedef _Float16 half4v __attribute__((ext_vector_type(4)));
typedef __fp16   fp16x2 __attribute__((ext_vector_type(2)));   // cvt_pkrtz native type
typedef float    f32x4  __attribute__((ext_vector_type(4)));

// 0.125 * log2(e): QK^T scores come out in log2 units -> softmax via exp2 (no mul)
#define QSCALE 0.18033688011112042f

__device__ __forceinline__ void load_lds16(const _Float16* g, _Float16* l) {
  __builtin_amdgcn_global_load_lds(
      (const __attribute__((address_space(1))) void*)g,
      (__attribute__((address_space(3))) void*)l, 16, 0, 0);
}

// ---------------- fp32 -> fp16 convert ----------------
__global__ void cvt_f32_f16(const float* __restrict__ in, _Float16* __restrict__ out, int n) {
  int i = (blockIdx.x * 256 + threadIdx.x) * 4;
  if (i >= n) return;
  float4 v = *(const float4*)(in + i);
  half4v o;
  o.x = (_Float16)v.x; o.y = (_Float16)v.y; o.z = (_Float16)v.z; o.w = (_Float16)v.w;
  *(half4v*)(out + i) = o;
}

// ---------------- GEMM: C[r][f] = sum_k A[r][k] * W[f][k] ----------------
// MODE 0: QKV projection epilogue -> scatter q (scaled by 0.125*log2e), k to
//         [B,H,N,D], v to [B,H,D,N].  MODE 1: fp32 out[r][f] + bias[f].
template <int MODE, int GX>
__global__ __launch_bounds__(256, 2) void gemm_f16(
    const _Float16* __restrict__ A, const _Float16* __restrict__ W,
    _Float16* __restrict__ qo, _Float16* __restrict__ ko, _Float16* __restrict__ vo,
    float* __restrict__ out, const float* __restrict__ bias) {
  __shared__ __align__(16) _Float16 As[128 * 64];
  __shared__ __align__(16) _Float16 Bs[128 * 64];

  const int tid  = threadIdx.x;
  const int wave = tid >> 6;
  const int lane = tid & 63;
  const int wm = wave >> 1, wn = wave & 1;
  const int l15 = lane & 15, lg = lane >> 4;

  // XCD-chunked swizzle (nwg % 8 == 0 for both launches)
  const int nwg = GX * gridDim.y;
  int id = blockIdx.y * GX + blockIdx.x;
  id = (id & 7) * (nwg >> 3) + (id >> 3);
  const int rowBase = (id / GX) * 128;
  const int colBase = (id % GX) * 128;

  const f32x4 fzero = {0.f, 0.f, 0.f, 0.f};
  f32x4 acc[4][4];
#pragma unroll
  for (int m = 0; m < 4; ++m)
#pragma unroll
    for (int n = 0; n < 4; ++n) acc[m][n] = fzero;

  for (int kt = 0; kt < CDIM; kt += 64) {
    __syncthreads();
#pragma unroll
    for (int p = 0; p < 4; ++p) {
      int c = tid + p * 256;
      int r = c >> 3, cb = (c & 7) * 8;  // 8 chunks of 16B per 64-elem row
      load_lds16(A + (size_t)(rowBase + r) * CDIM + kt + cb, As + c * 8);
      load_lds16(W + (size_t)(colBase + r) * CDIM + kt + cb, Bs + c * 8);
    }
    __syncthreads();
#pragma unroll
    for (int ks = 0; ks < 2; ++ks) {
      half8 af[4], bf[4];
#pragma unroll
      for (int m = 0; m < 4; ++m)
        af[m] = *(const half8*)(As + (wm * 64 + m * 16 + l15) * 64 + ks * 32 + lg * 8);
#pragma unroll
      for (int n = 0; n < 4; ++n)
        bf[n] = *(const half8*)(Bs + (wn * 64 + n * 16 + l15) * 64 + ks * 32 + lg * 8);
#pragma unroll
      for (int m = 0; m < 4; ++m)
#pragma unroll
        for (int n = 0; n < 4; ++n)
          acc[m][n] = __builtin_amdgcn_mfma_f32_16x16x32_f16(af[m], bf[n], acc[m][n], 0, 0, 0);
    }
  }

  // Epilogue. C/D frag: col = lane&15, row = (lane>>4)*4 + g
  if constexpr (MODE == 0) {
#pragma unroll
    for (int m = 0; m < 4; ++m) {
#pragma unroll
      for (int n = 0; n < 4; ++n) {
        int f = colBase + wn * 64 + n * 16 + l15;      // 0..2303
        int which = f / CDIM;                          // uniform per (m,n)
        int fr = f - which * CDIM;
        int h = fr >> 6, d = fr & 63;
        int r0 = rowBase + wm * 64 + m * 16 + lg * 4;  // 4 consecutive rows
        int b = r0 >> 11, nn = r0 & 2047;              // never crosses 2048
        size_t bh = (size_t)(b * NH + h);
        if (which == 2) {
          // v: [B,H,D,N] -> the 4 g-values are consecutive n -> one 8B store
          half4v vv;
#pragma unroll
          for (int g = 0; g < 4; ++g) vv[g] = (_Float16)acc[m][n][g];
          *(half4v*)(vo + ((bh * HD + d) * SEQ + nn)) = vv;
        } else {
#pragma unroll
          for (int g = 0; g < 4; ++g) {
            float v = acc[m][n][g];
            if (which == 0) qo[(bh * SEQ + nn + g) * HD + d] = (_Float16)(v * QSCALE);
            else            ko[(bh * SEQ + nn + g) * HD + d] = (_Float16)v;
          }
        }
      }
    }
  } else {
#pragma unroll
    for (int m = 0; m < 4; ++m) {
#pragma unroll
      for (int n = 0; n < 4; ++n) {
        int f = colBase + wn * 64 + n * 16 + l15;
        float bv = bias[f];
#pragma unroll
        for (int g = 0; g < 4; ++g) {
          int r = rowBase + wm * 64 + m * 16 + lg * 4 + g;
          out[(size_t)r * CDIM + f] = acc[m][n][g] + bv;
        }
      }
    }
  }
}

// ---------------- Flash attention ----------------
// block = 512 (8 waves), grid = 768. Wave owns 32 q-rows; lane owns 2 queries.
// KEY-PERMUTED K staging (as round 7): concat(exp(st[2kb]),exp(st[2kb+1])) IS
// the 16x16x32 B-frag for PV -> PV = 16 x mfma_16x16x32, V read as b128.
// V LDS: linear [64][64] rows (128B = exactly 32 banks) + 3-bit XOR granule
// swizzle on BOTH sides (write granule sa^(sr&7), read granule
// (kbk*4+lg)^(d&7)) -> identical bank structure to the K reads, which measure
// ZERO conflicts (round-7's 144B-pad V was 4-way: 6.29M counted cycles).
// P packing via v_cvt_pkrtz_f16_f32 (2 f32 -> packed 2xf16, one instr).
// Softmax: C-init = -mo, ones-MFMA row sum, sum-overflow defer check, raw exp2.
__global__ __launch_bounds__(512, 4) void attn_f16(
    const _Float16* __restrict__ qb, const _Float16* __restrict__ kb,
    const _Float16* __restrict__ vt, _Float16* __restrict__ ob) {
  __shared__ __align__(16) _Float16 Ks[2][64 * 64];
  __shared__ __align__(16) _Float16 Vs[2][64 * 64];

  const int tid  = threadIdx.x;
  const int wave = tid >> 6;
  const int lane = tid & 63;
  const int l15 = lane & 15, lg = lane >> 4;

  // XCD-chunked mapping: xcd = i&7 owns 12 heads x all 8 q-tiles
  const int i = blockIdx.y * gridDim.x + blockIdx.x;  // 0..767
  const int w = i >> 3;                               // 0..95
  const int bh = (i & 7) * NH + (w % NH);
  const int qt = w / NH;                              // 0..7

  const _Float16* qp = qb + (size_t)bh * SEQ * HD;
  const _Float16* kp = kb + (size_t)bh * SEQ * HD;
  const _Float16* vp = vt + (size_t)bh * SEQ * HD;  // Vt: [64 d][2048 keys]

  // Q fragments (pre-scaled): B-frag n = l15 = q, k = lg*8+j
  half8 qf[2][2];
#pragma unroll
  for (int qb2 = 0; qb2 < 2; ++qb2) {
    int qrow = qt * 256 + wave * 32 + qb2 * 16 + l15;
    qf[qb2][0] = *(const half8*)(qp + (size_t)qrow * HD + lg * 8);
    qf[qb2][1] = *(const half8*)(qp + (size_t)qrow * HD + 32 + lg * 8);
  }

  const f32x4 fzero = {0.f, 0.f, 0.f, 0.f};
  const _Float16 h1 = (_Float16)1.f;
  const half8 ones8 = {h1, h1, h1, h1, h1, h1, h1, h1};
  f32x4 o[2][4];
#pragma unroll
  for (int qb2 = 0; qb2 < 2; ++qb2)
#pragma unroll
    for (int dt = 0; dt < 4; ++dt) o[qb2][dt] = fzero;
  f32x4 minit[2] = {fzero, fzero};   // = -mo (log2 units), per-query
  float ls[2] = {0.f, 0.f};          // exact per-query sum

  // staging indices (tid 0..511 covers each 64-row tile once)
  const int sr = tid >> 3;            // LDS row (K) / d-row (V), 0..63
  const int sa = tid & 7;             // 16B chunk index, 0..7
  // K row permutation: LDS row sr <- global key kperm(sr)
  const int kt_ = sr >> 4, km = sr & 15;
  const int kperm = ((kt_ >> 1) << 5) + ((km >> 2) << 3) + ((kt_ & 1) << 2) + (km & 3);
  const size_t kgoff = (size_t)kperm * HD + (((sa * 16) ^ ((sr & 7) << 4)) >> 1);
  const size_t vgoff = (size_t)sr * SEQ + sa * 8;            // keys linear
  _Float16* const ksdst = (_Float16*)Ks + (size_t)tid * 8;   // + buf*4096
  // V dest: linear row, XOR'd granule (content = keys sa*8..sa*8+7)
  _Float16* const vdst  = (_Float16*)Vs + sr * 64 + ((sa ^ (sr & 7)) * 8);  // + buf*4096
  uint4 vreg;

  auto kv_issue = [&](int dstBuf, int kt) {
    load_lds16(kp + (size_t)kt * 64 * HD + kgoff, ksdst + dstBuf * 4096);
    vreg = *(const uint4*)(vp + vgoff + kt * 64);
  };
  auto v_commit = [&](int dstBuf) {
    *(uint4*)(vdst + dstBuf * 4096) = vreg;   // single ds_write_b128
  };

  kv_issue(0, 0);
  v_commit(0);
  __syncthreads();
  int buf = 0;

  const float TH = 4096.0f;  // defer window 2^12; pv <= sum <= TH fits f16
  const int NT = SEQ / 64;
  for (int kt = 0; kt < NT; ++kt) {
    if (kt + 1 < NT) kv_issue(buf ^ 1, kt + 1);  // loads in flight over compute

    // ---- S^T - mo = K @ Q^T + (-mo) : C-init carries the softmax shift
    f32x4 st[2][4];
    __builtin_amdgcn_s_setprio(1);
#pragma unroll
    for (int ct = 0; ct < 4; ++ct) {
      int krow = ct * 16 + l15;
      const char* kbase = (const char*)&Ks[buf][0] + krow * 128;
      half8 kf0 = *(const half8*)(kbase + ((lg * 16) ^ ((krow & 7) << 4)));
      half8 kf1 = *(const half8*)(kbase + ((64 + lg * 16) ^ ((krow & 7) << 4)));
#pragma unroll
      for (int qb2 = 0; qb2 < 2; ++qb2) {
        st[qb2][ct] = __builtin_amdgcn_mfma_f32_16x16x32_f16(kf0, qf[qb2][0], minit[qb2], 0, 0, 0);
        st[qb2][ct] = __builtin_amdgcn_mfma_f32_16x16x32_f16(kf1, qf[qb2][1], st[qb2][ct], 0, 0, 0);
      }
    }
    __builtin_amdgcn_s_setprio(0);

    // ---- P = exp2(st), packed via v_cvt_pkrtz directly as PV B-frags
    //      (element j of half kbk = st[2kbk + (j>>2)][j&3]); ones-MFMA row sum
    half8 pvb[2][2];
    f32x4 osum[2];
#pragma unroll
    for (int qb2 = 0; qb2 < 2; ++qb2) {
#pragma unroll
      for (int kbk = 0; kbk < 2; ++kbk) {
        union { half8 v8; fp16x2 h2[4]; } u;
#pragma unroll
        for (int j2 = 0; j2 < 4; ++j2)
          u.h2[j2] = __builtin_amdgcn_cvt_pkrtz(
              __builtin_amdgcn_exp2f(st[qb2][2 * kbk + (j2 >> 1)][(j2 & 1) * 2]),
              __builtin_amdgcn_exp2f(st[qb2][2 * kbk + (j2 >> 1)][(j2 & 1) * 2 + 1]));
        pvb[qb2][kbk] = u.v8;
      }
      osum[qb2] = __builtin_amdgcn_mfma_f32_16x16x32_f16(ones8, pvb[qb2][0], fzero, 0, 0, 0);
      osum[qb2] = __builtin_amdgcn_mfma_f32_16x16x32_f16(ones8, pvb[qb2][1], osum[qb2], 0, 0, 0);
    }

    // ---- overflow check on the sum (inf/NaN fail the <=) -> rare fixup
    if (!__all((osum[0][0] <= TH) && (osum[1][0] <= TH))) {
#pragma unroll
      for (int qb2 = 0; qb2 < 2; ++qb2) {
        float gm = st[qb2][0][0];
#pragma unroll
        for (int ct = 0; ct < 4; ++ct)
#pragma unroll
          for (int g = 0; g < 4; ++g) gm = fmaxf(gm, st[qb2][ct][g]);
        gm = fmaxf(gm, __shfl_xor(gm, 16));
        gm = fmaxf(gm, __shfl_xor(gm, 32));
        float d = fmaxf(gm, 0.0f);                    // shift so new max -> 0
        float al = __builtin_amdgcn_exp2f(-d);
        ls[qb2] *= al;
#pragma unroll
        for (int dt = 0; dt < 4; ++dt) o[qb2][dt] *= al;
        minit[qb2] = minit[qb2] - d;
#pragma unroll
        for (int kbk = 0; kbk < 2; ++kbk) {
          union { half8 v8; fp16x2 h2[4]; } u;
#pragma unroll
          for (int j2 = 0; j2 < 4; ++j2)
            u.h2[j2] = __builtin_amdgcn_cvt_pkrtz(
                __builtin_amdgcn_exp2f(st[qb2][2 * kbk + (j2 >> 1)][(j2 & 1) * 2] - d),
                __builtin_amdgcn_exp2f(st[qb2][2 * kbk + (j2 >> 1)][(j2 & 1) * 2 + 1] - d));
          pvb[qb2][kbk] = u.v8;
        }
        osum[qb2] = __builtin_amdgcn_mfma_f32_16x16x32_f16(ones8, pvb[qb2][0], fzero, 0, 0, 0);
        osum[qb2] = __builtin_amdgcn_mfma_f32_16x16x32_f16(ones8, pvb[qb2][1], osum[qb2], 0, 0, 0);
      }
    }
    ls[0] += osum[0][0];
    ls[1] += osum[1][0];

    // ---- O^T += V @ P : A = V b128 frags (XOR'd granule), B = pvb in-reg
    __builtin_amdgcn_s_setprio(1);
#pragma unroll
    for (int kbk = 0; kbk < 2; ++kbk) {
#pragma unroll
      for (int dt = 0; dt < 4; ++dt) {
        int d = dt * 16 + l15;
        half8 vf = *(const half8*)((const char*)&Vs[buf][0] + d * 128 +
                                   (((kbk * 4 + lg) ^ (d & 7)) * 16));
        o[0][dt] = __builtin_amdgcn_mfma_f32_16x16x32_f16(vf, pvb[0][kbk], o[0][dt], 0, 0, 0);
        o[1][dt] = __builtin_amdgcn_mfma_f32_16x16x32_f16(vf, pvb[1][kbk], o[1][dt], 0, 0, 0);
      }
    }
    __builtin_amdgcn_s_setprio(0);

    if (kt + 1 < NT) v_commit(buf ^ 1);  // vmcnt wait + 1x ds_write_b128
    __syncthreads();                     // drains K-DMA too
    buf ^= 1;
  }

  // epilogue: lane holds O[q = qb2*16+l15][d = dt*16 + lg*4 + g]; ls is exact
  const int b = bh / NH, h = bh - b * NH;
#pragma unroll
  for (int qb2 = 0; qb2 < 2; ++qb2) {
    const float inv = 1.0f / ls[qb2];
    int q = qt * 256 + wave * 32 + qb2 * 16 + l15;
    size_t base = ((size_t)b * SEQ + q) * CDIM + h * HD;
#pragma unroll
    for (int dt = 0; dt < 4; ++dt) {
      half4v ov;
      ov.x = (_Float16)(o[qb2][dt][0] * inv); ov.y = (_Float16)(o[qb2][dt][1] * inv);
      ov.z = (_Float16)(o[qb2][dt][2] * inv); ov.w = (_Float16)(o[qb2][dt][3] * inv);
      *(half4v*)(ob + base + dt * 16 + lg * 4) = ov;
    }
  }
}

// ---------------- launch ----------------
extern "C" void kernel_launch(void* const* d_in, const int* in_sizes, int n_in,
                              void* d_out, int out_size, void* d_ws, size_t ws_size,
                              hipStream_t stream) {
  const float* x      = (const float*)d_in[0];  // [8,2048,768]
  const float* w_qkv  = (const float*)d_in[1];  // [2304,768]
  const float* w_proj = (const float*)d_in[2];  // [768,768]
  const float* b_proj = (const float*)d_in[3];  // [768]
  float* out = (float*)d_out;                   // [8,2048,768] fp32

  const size_t XN = (size_t)8 * SEQ * CDIM;     // 12,582,912
  const size_t WQ = (size_t)3 * CDIM * CDIM;    // 1,769,472
  const size_t WP = (size_t)CDIM * CDIM;        // 589,824

  _Float16* xb    = (_Float16*)d_ws;
  _Float16* wqkvb = xb + XN;
  _Float16* wpb   = wqkvb + WQ;
  _Float16* qb    = wpb + WP;
  _Float16* kb    = qb + XN;
  _Float16* vtb   = kb + XN;
  _Float16* ob    = vtb + XN;

  cvt_f32_f16<<<(int)(XN / 1024), 256, 0, stream>>>(x, xb, (int)XN);
  cvt_f32_f16<<<(int)(WQ / 1024), 256, 0, stream>>>(w_qkv, wqkvb, (int)WQ);
  cvt_f32_f16<<<(int)(WP / 1024), 256, 0, stream>>>(w_proj, wpb, (int)WP);

  // QKV: M=16384, Nf=2304  (grid 18x128 = 2304 blocks, %8==0)
  gemm_f16<0, 18><<<dim3(18, 128), 256, 0, stream>>>(
      xb, wqkvb, qb, kb, vtb, nullptr, nullptr);

  // attention: 8 q-tiles x 96 heads = 768 blocks
  attn_f16<<<dim3(SEQ / 256, 8 * NH), 512, 0, stream>>>(qb, kb, vtb, ob);

  // proj: M=16384, Nf=768  (grid 6x128 = 768 blocks, %8==0)
  gemm_f16<1, 6><<<dim3(6, 128), 256, 0, stream>>>(
      ob, wpb, nullptr, nullptr, nullptr, out, b_proj);
}